// Round 2
// baseline (165166.553 us; speedup 1.0000x reference)
//
#include <hip/hip_runtime.h>
#include <math.h>
#include <stdint.h>

// Problem constants: S=1024, B=64, I=512, H=512, 2 layers, fp32.
#define SEQ 1024
#define BATCH 64
#define HID 512
#define MROWS (SEQ * BATCH)   // 65536

// ---------------------------------------------------------------------------
// Input GEMM (unchanged from round 1 — verified correct):
// C[i,j] = sum_k A[i,k] * W[j,k] + b1[j] + b2[j]
// ---------------------------------------------------------------------------
#define BM 64
#define BN 64
#define BK 16
__launch_bounds__(256)
__global__ void gemm_bias(const float* __restrict__ A, const float* __restrict__ W,
                          const float* __restrict__ b1, const float* __restrict__ b2,
                          float* __restrict__ C) {
    __shared__ float As[BK][BM + 4];
    __shared__ float Ws[BK][BN + 4];

    const int bj = blockIdx.x % (HID / BN);
    const int bi = blockIdx.x / (HID / BN);
    const int tid = threadIdx.x;
    const int tx = tid % 16;
    const int ty = tid / 16;
    const int row0 = bi * BM;
    const int col0 = bj * BN;

    const int lr = tid / 4;
    const int lk = (tid % 4) * 4;

    float acc[4][4] = {};

    for (int k0 = 0; k0 < HID; k0 += BK) {
        float4 av = *(const float4*)(A + (size_t)(row0 + lr) * HID + k0 + lk);
        float4 wv = *(const float4*)(W + (size_t)(col0 + lr) * HID + k0 + lk);
        As[lk + 0][lr] = av.x; As[lk + 1][lr] = av.y;
        As[lk + 2][lr] = av.z; As[lk + 3][lr] = av.w;
        Ws[lk + 0][lr] = wv.x; Ws[lk + 1][lr] = wv.y;
        Ws[lk + 2][lr] = wv.z; Ws[lk + 3][lr] = wv.w;
        __syncthreads();
        #pragma unroll
        for (int k = 0; k < BK; ++k) {
            float4 a = *(const float4*)&As[k][ty * 4];
            float4 w = *(const float4*)&Ws[k][tx * 4];
            acc[0][0] += a.x * w.x; acc[0][1] += a.x * w.y; acc[0][2] += a.x * w.z; acc[0][3] += a.x * w.w;
            acc[1][0] += a.y * w.x; acc[1][1] += a.y * w.y; acc[1][2] += a.y * w.z; acc[1][3] += a.y * w.w;
            acc[2][0] += a.z * w.x; acc[2][1] += a.z * w.y; acc[2][2] += a.z * w.z; acc[2][3] += a.z * w.w;
            acc[3][0] += a.w * w.x; acc[3][1] += a.w * w.y; acc[3][2] += a.w * w.z; acc[3][3] += a.w * w.w;
        }
        __syncthreads();
    }

    #pragma unroll
    for (int c = 0; c < 4; ++c) {
        int col = col0 + tx * 4 + c;
        float bias = b1[col] + b2[col];
        #pragma unroll
        for (int r = 0; r < 4; ++r) {
            C[(size_t)(row0 + ty * 4 + r) * HID + col] = acc[r][c] + bias;
        }
    }
}

// ---------------------------------------------------------------------------
// Full-chip recurrence. Grid = 512 WGs = 64 col-slices (8 cols each) x 8
// batch-tiles (8 rows each). 256 threads/WG = 4 waves; wave w owns rows
// {8*bt+2w, 8*bt+2w+1}. Lane layout: j = lane&7 (col), kq = (lane>>3)&7
// (k-interleave class). Each thread holds W_hh[col][k : (k>>2)%8==kq] in 64
// VGPRs (loaded once). Per step: stage own 2 h-rows global->LDS, 128 FMAs,
// butterfly-reduce over kq lanes, tanh, store h_new + y, release flag.
// Cross-WG sync: monotone per-(bt,wave,c) step counters, agent scope.
// No __syncthreads in the step loop (LDS is wave-private).
// __launch_bounds__(256,2): 2 waves/EU -> 2 WGs/CU -> all 512 WGs resident
// (16KB LDS/WG, VGPR<=256) -> spin-wait cannot deadlock.
// ---------------------------------------------------------------------------
typedef const __attribute__((address_space(1))) void* gas_t;
typedef __attribute__((address_space(3))) void* las_t;

__device__ __forceinline__ void stage256(const float* src, float* ldst, int lane) {
    // 64 lanes x 16B -> 256 consecutive floats into LDS at ldst
    __builtin_amdgcn_global_load_lds((gas_t)(const void*)(src + 4 * lane),
                                     (las_t)(void*)ldst, 16, 0, 0);
}

__launch_bounds__(256, 2)
__global__ void rnn_rec2(float* __restrict__ UY,       // (S,B,H): in U, out y (in-place)
                         const float* __restrict__ W,  // W_hh (H,H) row-major
                         const float* __restrict__ h0, // (B,H) initial hidden
                         float* __restrict__ hbuf,     // (2,B,H) ping-pong
                         uint32_t* __restrict__ flags, // (8,4,64) monotone step counters
                         float* __restrict__ hT)       // (B,H) final hidden
{
    __shared__ float lds_h[8][HID];   // 16 KB, wave-private row pairs

    const int tid  = threadIdx.x;
    const int lane = tid & 63;
    const int w    = tid >> 6;            // wave id 0..3
    const int j    = lane & 7;
    const int kq   = (lane >> 3) & 7;
    const int c    = blockIdx.x & 63;     // col-slice id
    const int bt   = blockIdx.x >> 6;     // batch-tile id
    const int col  = c * 8 + j;
    const int r0   = bt * 8 + 2 * w;
    const int r1   = r0 + 1;

    // Register-resident W fragment: chunks m = kq + 8i, i in [0,16)
    float4 Wreg[16];
    #pragma unroll
    for (int i = 0; i < 16; ++i)
        Wreg[i] = *(const float4*)(W + (size_t)col * HID + 4 * (kq + 8 * i));

    uint32_t* fl = flags + (size_t)(bt * 4 + w) * 64;

    float* l0 = &lds_h[2 * w][0];
    float* l1 = &lds_h[2 * w + 1][0];

    for (int t = 0; t < SEQ; ++t) {
        const float* hsrc = (t == 0) ? h0 : (hbuf + (size_t)(t & 1) * BATCH * HID);
        float*       hdst = hbuf + (size_t)((t + 1) & 1) * BATCH * HID;

        // U prefetch: independent of flags, overlaps the spin
        const size_t ub0 = ((size_t)t * BATCH + r0) * HID + col;
        const size_t ub1 = ((size_t)t * BATCH + r1) * HID + col;
        float u0 = UY[ub0];
        float u1 = UY[ub1];

        if (t > 0) {
            // wait for wave w of all 64 col-slice WGs in group bt
            for (;;) {
                uint32_t f = __hip_atomic_load(&fl[lane], __ATOMIC_RELAXED,
                                               __HIP_MEMORY_SCOPE_AGENT);
                if (__all((int)(f >= (uint32_t)t))) break;
                __builtin_amdgcn_s_sleep(1);
            }
            __threadfence();  // acquire: invalidate stale L1/L2 before reading hbuf
        }

        // stage this wave's two h rows into wave-private LDS
        stage256(hsrc + (size_t)r0 * HID,       l0,       lane);
        stage256(hsrc + (size_t)r0 * HID + 256, l0 + 256, lane);
        stage256(hsrc + (size_t)r1 * HID,       l1,       lane);
        stage256(hsrc + (size_t)r1 * HID + 256, l1 + 256, lane);
        asm volatile("s_waitcnt vmcnt(0)" ::: "memory");

        // partial dot products over this thread's k-classes
        float s0 = 0.f, s1 = 0.f;
        #pragma unroll
        for (int i = 0; i < 16; ++i) {
            const int ko = 4 * kq + 32 * i;            // bank-quad kq -> conflict-free
            float4 h0v = *(const float4*)(l0 + ko);
            float4 h1v = *(const float4*)(l1 + ko);
            s0 += h0v.x * Wreg[i].x; s0 += h0v.y * Wreg[i].y;
            s0 += h0v.z * Wreg[i].z; s0 += h0v.w * Wreg[i].w;
            s1 += h1v.x * Wreg[i].x; s1 += h1v.y * Wreg[i].y;
            s1 += h1v.z * Wreg[i].z; s1 += h1v.w * Wreg[i].w;
        }

        // reduce over the 8 kq lanes (lane bits 3..5)
        s0 += __shfl_xor(s0, 8);  s1 += __shfl_xor(s1, 8);
        s0 += __shfl_xor(s0, 16); s1 += __shfl_xor(s1, 16);
        s0 += __shfl_xor(s0, 32); s1 += __shfl_xor(s1, 32);

        float v0 = tanhf(s0 + u0);
        float v1 = tanhf(s1 + u1);

        if (kq == 0) {   // lanes 0..7 hold the canonical copy
            hdst[(size_t)r0 * HID + col] = v0;
            hdst[(size_t)r1 * HID + col] = v1;
            UY[ub0] = v0;     // y output, in place over U
            UY[ub1] = v1;
            if (t == SEQ - 1) {
                hT[(size_t)r0 * HID + col] = v0;
                hT[(size_t)r1 * HID + col] = v1;
            }
        }

        __threadfence();  // release: drain stores + L2 writeback (cross-XCD)
        if (lane == 0)
            __hip_atomic_store(&fl[c], (uint32_t)(t + 1), __ATOMIC_RELAXED,
                               __HIP_MEMORY_SCOPE_AGENT);
    }
}

// ---------------------------------------------------------------------------
// Launch
// ---------------------------------------------------------------------------
extern "C" void kernel_launch(void* const* d_in, const int* in_sizes, int n_in,
                              void* d_out, int out_size, void* d_ws, size_t ws_size,
                              hipStream_t stream) {
    (void)in_sizes; (void)n_in; (void)out_size; (void)ws_size;

    const float* x      = (const float*)d_in[0];   // (S,B,I)
    const float* hx     = (const float*)d_in[1];   // (2,B,H)
    const float* W_ih0  = (const float*)d_in[2];   // (H,I)
    const float* W_hh0  = (const float*)d_in[3];   // (H,H)
    const float* b_ih0  = (const float*)d_in[4];
    const float* b_hh0  = (const float*)d_in[5];
    const float* W_ih1  = (const float*)d_in[6];   // (H,H)
    const float* W_hh1  = (const float*)d_in[7];   // (H,H)
    const float* b_ih1  = (const float*)d_in[8];
    const float* b_hh1  = (const float*)d_in[9];

    float* out = (float*)d_out;
    float* y1   = out;                                  // (S,B,H)
    float* hT0  = out + (size_t)SEQ * BATCH * HID;      // (B,H)
    float* hT1  = hT0 + (size_t)BATCH * HID;            // (B,H)

    // Workspace: U0 (134MB) | hbuf (256KB) | flags0 (8KB) | flags1 (8KB)
    float*    U0     = (float*)d_ws;
    float*    hbuf   = U0 + (size_t)MROWS * HID;
    uint32_t* flags0 = (uint32_t*)(hbuf + 2 * (size_t)BATCH * HID);
    uint32_t* flags1 = flags0 + 8 * 4 * 64;

    // flags are spin targets — must start at 0 (ws is poisoned 0xAA)
    hipMemsetAsync(flags0, 0, 2 * 8 * 4 * 64 * sizeof(uint32_t), stream);

    // Layer 0: U0 = x @ W_ih0^T + b_ih0 + b_hh0
    gemm_bias<<<(MROWS / BM) * (HID / BN), 256, 0, stream>>>(x, W_ih0, b_ih0, b_hh0, U0);
    rnn_rec2<<<512, 256, 0, stream>>>(U0, W_hh0, hx, hbuf, flags0, hT0);

    // Layer 1: U1 = y0 @ W_ih1^T + b_ih1 + b_hh1 (into d_out y1 region)
    gemm_bias<<<(MROWS / BM) * (HID / BN), 256, 0, stream>>>(U0, W_ih1, b_ih1, b_hh1, y1);
    rnn_rec2<<<512, 256, 0, stream>>>(y1, W_hh1, hx + (size_t)BATCH * HID, hbuf, flags1, hT1);
}

// Round 3
// 85658.246 us; speedup vs baseline: 1.9282x; 1.9282x over previous
//
#include <hip/hip_runtime.h>
#include <math.h>
#include <stdint.h>

// Problem constants: S=1024, B=64, I=512, H=512, 2 layers, fp32.
#define SEQ 1024
#define BATCH 64
#define HID 512
#define MROWS (SEQ * BATCH)   // 65536

// ---------------------------------------------------------------------------
// Input GEMM (unchanged, verified): C[i,j] = sum_k A[i,k]*W[j,k] + b1[j] + b2[j]
// ---------------------------------------------------------------------------
#define BM 64
#define BN 64
#define BK 16
__launch_bounds__(256)
__global__ void gemm_bias(const float* __restrict__ A, const float* __restrict__ W,
                          const float* __restrict__ b1, const float* __restrict__ b2,
                          float* __restrict__ C) {
    __shared__ float As[BK][BM + 4];
    __shared__ float Ws[BK][BN + 4];

    const int bj = blockIdx.x % (HID / BN);
    const int bi = blockIdx.x / (HID / BN);
    const int tid = threadIdx.x;
    const int tx = tid % 16;
    const int ty = tid / 16;
    const int row0 = bi * BM;
    const int col0 = bj * BN;
    const int lr = tid / 4;
    const int lk = (tid % 4) * 4;

    float acc[4][4] = {};

    for (int k0 = 0; k0 < HID; k0 += BK) {
        float4 av = *(const float4*)(A + (size_t)(row0 + lr) * HID + k0 + lk);
        float4 wv = *(const float4*)(W + (size_t)(col0 + lr) * HID + k0 + lk);
        As[lk + 0][lr] = av.x; As[lk + 1][lr] = av.y;
        As[lk + 2][lr] = av.z; As[lk + 3][lr] = av.w;
        Ws[lk + 0][lr] = wv.x; Ws[lk + 1][lr] = wv.y;
        Ws[lk + 2][lr] = wv.z; Ws[lk + 3][lr] = wv.w;
        __syncthreads();
        #pragma unroll
        for (int k = 0; k < BK; ++k) {
            float4 a = *(const float4*)&As[k][ty * 4];
            float4 w = *(const float4*)&Ws[k][tx * 4];
            acc[0][0] += a.x * w.x; acc[0][1] += a.x * w.y; acc[0][2] += a.x * w.z; acc[0][3] += a.x * w.w;
            acc[1][0] += a.y * w.x; acc[1][1] += a.y * w.y; acc[1][2] += a.y * w.z; acc[1][3] += a.y * w.w;
            acc[2][0] += a.z * w.x; acc[2][1] += a.z * w.y; acc[2][2] += a.z * w.z; acc[2][3] += a.z * w.w;
            acc[3][0] += a.w * w.x; acc[3][1] += a.w * w.y; acc[3][2] += a.w * w.z; acc[3][3] += a.w * w.w;
        }
        __syncthreads();
    }

    #pragma unroll
    for (int c = 0; c < 4; ++c) {
        int col = col0 + tx * 4 + c;
        float bias = b1[col] + b2[col];
        #pragma unroll
        for (int r = 0; r < 4; ++r) {
            C[(size_t)(row0 + ty * 4 + r) * HID + col] = acc[r][c] + bias;
        }
    }
}

// ---------------------------------------------------------------------------
// Pack W_hh (H,H fp32, row-major [col j][k]) into bf16 pairs laid out in the
// exact order rnn_rec3 reads: element index (q*1024 + T), q in [0,32),
// T = consumer thread id. Thread T owns cols {2c, 2c+1} (c=T>>2) and
// k in [128*kq, 128*kq+128) (kq=T&3). q = 2*m + s: mini-iter m in [0,16),
// col-select s. Each uint4 = 8 weights of col (2c+s), k = 128kq+8m .. +8,
// packed as uint32 = bf16(k even) | bf16(k odd)<<16.
// ---------------------------------------------------------------------------
__device__ __forceinline__ uint32_t f2bf(float f) {
    uint32_t u = __float_as_uint(f);
    uint32_t r = ((u >> 16) & 1u) + 0x7FFFu;   // round-to-nearest-even
    return (u + r) >> 16;
}

__launch_bounds__(256)
__global__ void prep_w(const float* __restrict__ W, uint4* __restrict__ Wq) {
    int gid = blockIdx.x * 256 + threadIdx.x;   // [0, 32768)
    int T = gid & 1023;
    int q = gid >> 10;
    int m = q >> 1;
    int s = q & 1;
    int c = T >> 2;
    int kq = T & 3;
    int j = 2 * c + s;
    int k0 = 128 * kq + 8 * m;
    const float* src = W + (size_t)j * HID + k0;
    uint32_t p0 = f2bf(src[0]) | (f2bf(src[1]) << 16);
    uint32_t p1 = f2bf(src[2]) | (f2bf(src[3]) << 16);
    uint32_t p2 = f2bf(src[4]) | (f2bf(src[5]) << 16);
    uint32_t p3 = f2bf(src[6]) | (f2bf(src[7]) << 16);
    Wq[gid] = make_uint4(p0, p1, p2, p3);
}

// ---------------------------------------------------------------------------
// Recurrence: one WG (1024 threads = 16 waves) per batch element. No cross-WG
// communication of any kind. h ping-pongs in LDS (4KB); W_hh streamed from L2
// as packed bf16 (512KB/step/CU) in fully-coalesced uint4 loads; fp32 FMA.
// Thread T: cols j0=2c, j0+1 (c=T>>2), k-range [128kq,128kq+128) (kq=T&3);
// 4-way k-split reduced in-wave via shfl_xor(1),(2). One __syncthreads/step.
// ---------------------------------------------------------------------------
__device__ __forceinline__ float blo(uint32_t w) { return __uint_as_float(w << 16); }
__device__ __forceinline__ float bhi(uint32_t w) { return __uint_as_float(w & 0xFFFF0000u); }

__launch_bounds__(1024)
__global__ void rnn_rec3(float* __restrict__ UY,        // (S,B,H): in U, out y (in place)
                         const uint4* __restrict__ Wq,  // packed bf16 W_hh, consumer order
                         const float* __restrict__ h0,  // (B,H)
                         float* __restrict__ hT)        // (B,H)
{
    __shared__ float hA[HID], hB[HID];
    const int tid = threadIdx.x;
    const int b   = blockIdx.x;
    const int c   = tid >> 2;
    const int kq  = tid & 3;
    const int j0  = 2 * c;
    const int kb  = 128 * kq;

    if (tid < 128)
        *(float4*)(hA + 4 * tid) = *(const float4*)(h0 + (size_t)b * HID + 4 * tid);
    __syncthreads();

    const uint4* wp = Wq + tid;   // stride 1024 uint4 per q

    for (int t = 0; t < SEQ; ++t) {
        float* cur = (t & 1) ? hB : hA;
        float* nxt = (t & 1) ? hA : hB;
        const size_t ubase = ((size_t)t * BATCH + b) * HID + j0;
        float2 u = *(const float2*)(UY + ubase);

        float s0 = 0.f, s1 = 0.f;
        #pragma unroll
        for (int m = 0; m < 16; ++m) {
            float4 ha = *(const float4*)(cur + kb + 8 * m);
            float4 hb4 = *(const float4*)(cur + kb + 8 * m + 4);
            uint4 w0 = wp[(size_t)(2 * m) * 1024];
            uint4 w1 = wp[(size_t)(2 * m + 1) * 1024];
            s0 += blo(w0.x) * ha.x;  s0 += bhi(w0.x) * ha.y;
            s0 += blo(w0.y) * ha.z;  s0 += bhi(w0.y) * ha.w;
            s0 += blo(w0.z) * hb4.x; s0 += bhi(w0.z) * hb4.y;
            s0 += blo(w0.w) * hb4.z; s0 += bhi(w0.w) * hb4.w;
            s1 += blo(w1.x) * ha.x;  s1 += bhi(w1.x) * ha.y;
            s1 += blo(w1.y) * ha.z;  s1 += bhi(w1.y) * ha.w;
            s1 += blo(w1.z) * hb4.x; s1 += bhi(w1.z) * hb4.y;
            s1 += blo(w1.w) * hb4.z; s1 += bhi(w1.w) * hb4.w;
        }

        // reduce the 4-way k-split (lanes kq = tid&3 are adjacent)
        s0 += __shfl_xor(s0, 1); s0 += __shfl_xor(s0, 2);
        s1 += __shfl_xor(s1, 1); s1 += __shfl_xor(s1, 2);

        if (kq == 0) {
            float v0 = tanhf(s0 + u.x);
            float v1 = tanhf(s1 + u.y);
            nxt[j0]     = v0;
            nxt[j0 + 1] = v1;
            *(float2*)(UY + ubase) = make_float2(v0, v1);
        }
        __syncthreads();
    }

    // t=1023 wrote nxt = hA
    if (tid < 128)
        *(float4*)(hT + (size_t)b * HID + 4 * tid) = *(const float4*)(hA + 4 * tid);
}

// ---------------------------------------------------------------------------
// Launch
// ---------------------------------------------------------------------------
extern "C" void kernel_launch(void* const* d_in, const int* in_sizes, int n_in,
                              void* d_out, int out_size, void* d_ws, size_t ws_size,
                              hipStream_t stream) {
    (void)in_sizes; (void)n_in; (void)out_size; (void)ws_size;

    const float* x      = (const float*)d_in[0];   // (S,B,I)
    const float* hx     = (const float*)d_in[1];   // (2,B,H)
    const float* W_ih0  = (const float*)d_in[2];   // (H,I)
    const float* W_hh0  = (const float*)d_in[3];   // (H,H)
    const float* b_ih0  = (const float*)d_in[4];
    const float* b_hh0  = (const float*)d_in[5];
    const float* W_ih1  = (const float*)d_in[6];   // (H,H)
    const float* W_hh1  = (const float*)d_in[7];   // (H,H)
    const float* b_ih1  = (const float*)d_in[8];
    const float* b_hh1  = (const float*)d_in[9];

    float* out = (float*)d_out;
    float* y1   = out;                                  // (S,B,H)
    float* hT0  = out + (size_t)SEQ * BATCH * HID;      // (B,H)
    float* hT1  = hT0 + (size_t)BATCH * HID;            // (B,H)

    // Workspace: Wq0 (512KB) | Wq1 (512KB) | U0 (134MB)
    uint4* Wq0 = (uint4*)d_ws;
    uint4* Wq1 = Wq0 + 32768;
    float* U0  = (float*)(Wq1 + 32768);

    // pack both W_hh
    prep_w<<<128, 256, 0, stream>>>(W_hh0, Wq0);
    prep_w<<<128, 256, 0, stream>>>(W_hh1, Wq1);

    // Layer 0
    gemm_bias<<<(MROWS / BM) * (HID / BN), 256, 0, stream>>>(x, W_ih0, b_ih0, b_hh0, U0);
    rnn_rec3<<<BATCH, 1024, 0, stream>>>(U0, Wq0, hx, hT0);

    // Layer 1
    gemm_bias<<<(MROWS / BM) * (HID / BN), 256, 0, stream>>>(U0, W_ih1, b_ih1, b_hh1, y1);
    rnn_rec3<<<BATCH, 1024, 0, stream>>>(y1, Wq1, hx + (size_t)BATCH * HID, hT1);
}